// Round 2
// baseline (177.790 us; speedup 1.0000x reference)
//
#include <hip/hip_runtime.h>

// Median blur 3x3, replicate borders, NHWC fp32 [B, 512, 512, 3].
// Exact median-of-9: per-row (min3, med3, max3) triples, then
//   med9 = med3( max3(mins), med3(meds), min3(maxes) )
// v2: float4-vectorized. Each thread owns one 16B-aligned float4 column
// (384 threads cover the full 1536-float row). Horizontal +-3 neighbors
// come from register components of three aligned float4 loads (M-4, M, M+4):
//   l0..l2 = L.y,L.z,L.w   l3 = M.x   (l3 never needs L)
//   r1..r3 = R.x,R.y,R.z   r0 = M.w   (r0 never needs R)
// Edge replicate only affects thread 0 (l0..l2 -> M.x..M.z) and thread 383
// (r1..r3 -> M.y..M.w) -> per-lane cndmask, no divergent control flow.
// This cuts global memory instructions 4x vs the scalar version (16B/lane).

#define IMG_H 512
#define IMG_W 512
#define IMG_C 3
#define ROW_F (IMG_W * IMG_C)   // 1536 floats per row
#define TILE_H 8                // rows per thread (vertical rolling window)
#define TPB (ROW_F / 4)         // 384 threads = 6 waves, one float4 each

__device__ __forceinline__ float med3f(float a, float b, float c) {
    return __builtin_amdgcn_fmed3f(a, b, c);
}
__device__ __forceinline__ float min3f(float a, float b, float c) {
    return fminf(fminf(a, b), c);
}
__device__ __forceinline__ float max3f(float a, float b, float c) {
    return fmaxf(fmaxf(a, b), c);
}

__global__ __launch_bounds__(TPB) void median3x3_v2(
        const float* __restrict__ in, float* __restrict__ out) {
    const int t  = threadIdx.x;          // 0..383
    const int b  = blockIdx.z;
    const int h0 = blockIdx.y * TILE_H;

    const float* base  = in  + (size_t)b * IMG_H * ROW_F + t * 4;
    float*       obase = out + (size_t)b * IMG_H * ROW_F + t * 4;

    const bool le = (t == 0);
    const bool re = (t == TPB - 1);
    const int  dl = le ? 0 : 4;          // clamp pointer, no OOB at t==0
    const int  dr = re ? 0 : 4;

    // Rolling per-row triples for 4 columns each: all statically indexed
    // (loop fully unrolled) so everything stays in registers.
    float mn[3][4], md[3][4], mx[3][4];

    auto loadrow = [&](int r, int s) {
        const float* p = base + (size_t)r * ROW_F;
        const float4 M = *(const float4*)p;
        const float4 L = *(const float4*)(p - dl);
        const float4 R = *(const float4*)(p + dr);
        const float l0 = le ? M.x : L.y;
        const float l1 = le ? M.y : L.z;
        const float l2 = le ? M.z : L.w;
        const float l3 = M.x;            // wc-3 of column 3 is column 0
        const float r0 = M.w;            // wc+3 of column 0 is column 3
        const float r1 = re ? M.y : R.x;
        const float r2 = re ? M.z : R.y;
        const float r3 = re ? M.w : R.z;
        mn[s][0] = min3f(l0, M.x, r0); md[s][0] = med3f(l0, M.x, r0); mx[s][0] = max3f(l0, M.x, r0);
        mn[s][1] = min3f(l1, M.y, r1); md[s][1] = med3f(l1, M.y, r1); mx[s][1] = max3f(l1, M.y, r1);
        mn[s][2] = min3f(l2, M.z, r2); md[s][2] = med3f(l2, M.z, r2); mx[s][2] = max3f(l2, M.z, r2);
        mn[s][3] = min3f(l3, M.w, r3); md[s][3] = med3f(l3, M.w, r3); mx[s][3] = max3f(l3, M.w, r3);
    };

    // Prime the rolling window: rows h0-1 (clamped) and h0.
    loadrow((h0 == 0) ? 0 : h0 - 1, 0);
    loadrow(h0, 1);

    #pragma unroll
    for (int i = 0; i < TILE_H; ++i) {
        const int h  = h0 + i;
        const int hp = (h == IMG_H - 1) ? h : h + 1;   // replicate bottom edge
        const int s0 = i % 3, s1 = (i + 1) % 3, s2 = (i + 2) % 3;
        loadrow(hp, s2);

        float4 o;
        o.x = med3f(max3f(mn[s0][0], mn[s1][0], mn[s2][0]),
                    med3f(md[s0][0], md[s1][0], md[s2][0]),
                    min3f(mx[s0][0], mx[s1][0], mx[s2][0]));
        o.y = med3f(max3f(mn[s0][1], mn[s1][1], mn[s2][1]),
                    med3f(md[s0][1], md[s1][1], md[s2][1]),
                    min3f(mx[s0][1], mx[s1][1], mx[s2][1]));
        o.z = med3f(max3f(mn[s0][2], mn[s1][2], mn[s2][2]),
                    med3f(md[s0][2], md[s1][2], md[s2][2]),
                    min3f(mx[s0][2], mx[s1][2], mx[s2][2]));
        o.w = med3f(max3f(mn[s0][3], mn[s1][3], mn[s2][3]),
                    med3f(md[s0][3], md[s1][3], md[s2][3]),
                    min3f(mx[s0][3], mx[s1][3], mx[s2][3]));
        *(float4*)(obase + (size_t)h * ROW_F) = o;
    }
}

extern "C" void kernel_launch(void* const* d_in, const int* in_sizes, int n_in,
                              void* d_out, int out_size, void* d_ws, size_t ws_size,
                              hipStream_t stream) {
    const float* in = (const float*)d_in[0];
    float* out = (float*)d_out;

    const int B = in_sizes[0] / (IMG_H * ROW_F);   // 32

    dim3 grid(1, IMG_H / TILE_H, B);               // (1, 64, 32) = 2048 blocks
    dim3 block(TPB, 1, 1);
    median3x3_v2<<<grid, block, 0, stream>>>(in, out);
}

// Round 3
// 176.838 us; speedup vs baseline: 1.0054x; 1.0054x over previous
//
#include <hip/hip_runtime.h>

// Median blur 3x3, replicate borders, NHWC fp32 [B, 512, 512, 3].
// Exact median-of-9: per-row (min3, med3, max3) triples, then
//   med9 = med3( max3(mins), med3(meds), min3(maxes) )
//
// v3: phase-split for memory-level parallelism.
// v2 post-mortem: compiler minimized VGPRs (36) and serialized the rolling
// window into load3->wait->compute rounds (~3 loads in flight, 10 serial
// latency exposures per wave) -> 2.5 TB/s, latency-bound.
// v3 issues ALL 30 float4 loads (10 rows x L/M/R) up front with static
// indices, then computes; the compiler emits counted vmcnt waits and keeps
// ~30 loads in flight per wave. VGPR ~170 (3 waves/SIMD) is intentional:
// ILP replaces TLP for latency hiding.

#define IMG_H 512
#define IMG_W 512
#define IMG_C 3
#define ROW_F (IMG_W * IMG_C)   // 1536 floats per row
#define TILE_H 8                // output rows per thread
#define NROWS (TILE_H + 2)      // input rows needed (10)
#define TPB (ROW_F / 4)         // 384 threads = 6 waves, one float4 column each

__device__ __forceinline__ float med3f(float a, float b, float c) {
    return __builtin_amdgcn_fmed3f(a, b, c);
}
__device__ __forceinline__ float min3f(float a, float b, float c) {
    return fminf(fminf(a, b), c);
}
__device__ __forceinline__ float max3f(float a, float b, float c) {
    return fmaxf(fmaxf(a, b), c);
}

__global__ __launch_bounds__(TPB) void median3x3_v3(
        const float* __restrict__ in, float* __restrict__ out) {
    const int t  = threadIdx.x;          // 0..383
    const int b  = blockIdx.z;
    const int h0 = blockIdx.y * TILE_H;

    const float* base  = in  + (size_t)b * IMG_H * ROW_F + t * 4;
    float*       obase = out + (size_t)b * IMG_H * ROW_F + t * 4;

    const bool le = (t == 0);
    const bool re = (t == TPB - 1);
    const int  dl = le ? 0 : 4;          // clamp pointer, no OOB at t==0
    const int  dr = re ? 0 : 4;

    // -------- Phase A: issue every load for the tile, back-to-back --------
    // All indices are compile-time after unroll -> registers, no scratch.
    float4 Lr[NROWS], Mr[NROWS], Rr[NROWS];
    #pragma unroll
    for (int r = 0; r < NROWS; ++r) {
        int row = h0 - 1 + r;
        row = (row < 0) ? 0 : row;                    // replicate top edge
        row = (row > IMG_H - 1) ? IMG_H - 1 : row;    // replicate bottom edge
        const float* p = base + (size_t)row * ROW_F;
        Mr[r] = *(const float4*)p;
        Lr[r] = *(const float4*)(p - dl);
        Rr[r] = *(const float4*)(p + dr);
    }

    // -------- Phase B: consume in order (counted vmcnt waits) --------
    // Rolling per-row triples for 4 columns each, statically indexed.
    float mn[3][4], md[3][4], mx[3][4];

    auto triple = [&](int r, int s) {
        const float4 M = Mr[r];
        const float4 L = Lr[r];
        const float4 R = Rr[r];
        const float l0 = le ? M.x : L.y;
        const float l1 = le ? M.y : L.z;
        const float l2 = le ? M.z : L.w;
        const float l3 = M.x;            // wc-3 of column 3 is column 0
        const float r0 = M.w;            // wc+3 of column 0 is column 3
        const float r1 = re ? M.y : R.x;
        const float r2 = re ? M.z : R.y;
        const float r3 = re ? M.w : R.z;
        mn[s][0] = min3f(l0, M.x, r0); md[s][0] = med3f(l0, M.x, r0); mx[s][0] = max3f(l0, M.x, r0);
        mn[s][1] = min3f(l1, M.y, r1); md[s][1] = med3f(l1, M.y, r1); mx[s][1] = max3f(l1, M.y, r1);
        mn[s][2] = min3f(l2, M.z, r2); md[s][2] = med3f(l2, M.z, r2); mx[s][2] = max3f(l2, M.z, r2);
        mn[s][3] = min3f(l3, M.w, r3); md[s][3] = med3f(l3, M.w, r3); mx[s][3] = max3f(l3, M.w, r3);
    };

    triple(0, 0);
    triple(1, 1);

    #pragma unroll
    for (int i = 0; i < TILE_H; ++i) {
        const int h  = h0 + i;
        const int s0 = i % 3, s1 = (i + 1) % 3, s2 = (i + 2) % 3;
        triple(i + 2, s2);

        float4 o;
        o.x = med3f(max3f(mn[s0][0], mn[s1][0], mn[s2][0]),
                    med3f(md[s0][0], md[s1][0], md[s2][0]),
                    min3f(mx[s0][0], mx[s1][0], mx[s2][0]));
        o.y = med3f(max3f(mn[s0][1], mn[s1][1], mn[s2][1]),
                    med3f(md[s0][1], md[s1][1], md[s2][1]),
                    min3f(mx[s0][1], mx[s1][1], mx[s2][1]));
        o.z = med3f(max3f(mn[s0][2], mn[s1][2], mn[s2][2]),
                    med3f(md[s0][2], md[s1][2], md[s2][2]),
                    min3f(mx[s0][2], mx[s1][2], mx[s2][2]));
        o.w = med3f(max3f(mn[s0][3], mn[s1][3], mn[s2][3]),
                    med3f(md[s0][3], md[s1][3], md[s2][3]),
                    min3f(mx[s0][3], mx[s1][3], mx[s2][3]));
        *(float4*)(obase + (size_t)h * ROW_F) = o;
    }
}

extern "C" void kernel_launch(void* const* d_in, const int* in_sizes, int n_in,
                              void* d_out, int out_size, void* d_ws, size_t ws_size,
                              hipStream_t stream) {
    const float* in = (const float*)d_in[0];
    float* out = (float*)d_out;

    const int B = in_sizes[0] / (IMG_H * ROW_F);   // 32

    dim3 grid(1, IMG_H / TILE_H, B);               // (1, 64, 32) = 2048 blocks
    dim3 block(TPB, 1, 1);
    median3x3_v3<<<grid, block, 0, stream>>>(in, out);
}

// Round 5
// 174.544 us; speedup vs baseline: 1.0186x; 1.0131x over previous
//
#include <hip/hip_runtime.h>

// Median blur 3x3, replicate borders, NHWC fp32 [B, 512, 512, 3].
// Exact median-of-9: per-row (min3, med3, max3) triples, then
//   med9 = med3( max3(mins), med3(meds), min3(maxes) )
//
// v4: single-visit reads + enforced memory-level parallelism.
// v3 post-mortem: VGPR_Count=40 proved the compiler SANK the phase-A loads
// back into the consume loop (needed ~150 VGPRs to hold them) -> identical
// 60us / 2.7 TB/s as v2. Two fixes, both on the read path:
//   1. Each thread loads ONLY its own float4 column per row (10 loads).
//      Horizontal +-3 neighbors come from __shfl_up/down (register
//      exchange). Wave-edge lanes (0,63), where shuffles can't reach,
//      fetch the adjacent float4 with an exec-masked load (2 lanes active).
//      -> 3x fewer read requests, all 128B-line aligned.
//   2. An empty `asm volatile` reads every loaded value after phase A:
//      a data dependence the compiler cannot sink the loads past. All
//      ~20 wave-load instructions stay issued back-to-back -> one wait.

#define IMG_H 512
#define IMG_W 512
#define IMG_C 3
#define ROW_F (IMG_W * IMG_C)   // 1536 floats per row
#define TILE_H 8                // output rows per thread
#define NROWS (TILE_H + 2)      // input rows touched (10)
#define TPB (ROW_F / 4)         // 384 threads = 6 waves, one float4 column each

__device__ __forceinline__ float med3f(float a, float b, float c) {
    return __builtin_amdgcn_fmed3f(a, b, c);
}
__device__ __forceinline__ float min3f(float a, float b, float c) {
    return fminf(fminf(a, b), c);
}
__device__ __forceinline__ float max3f(float a, float b, float c) {
    return fmaxf(fmaxf(a, b), c);
}

__device__ __forceinline__ int clampRow(int r) {
    return (r < 0) ? 0 : (r > IMG_H - 1 ? IMG_H - 1 : r);
}

__global__ __launch_bounds__(TPB) void median3x3_v4(
        const float* __restrict__ in, float* __restrict__ out) {
    const int t    = threadIdx.x;        // 0..383 (float4 column index)
    const int lane = t & 63;
    const int b    = blockIdx.z;
    const int h0   = blockIdx.y * TILE_H;

    const float* base  = in  + (size_t)b * IMG_H * ROW_F + t * 4;
    float*       obase = out + (size_t)b * IMG_H * ROW_F + t * 4;

    const bool lef = (lane == 0);        // wave-left edge: shfl_up invalid
    const bool rif = (lane == 63);       // wave-right edge: shfl_down invalid
    const bool il  = (t == 0);           // image left edge (replicate)
    const bool ir  = (t == TPB - 1);     // image right edge (replicate)

    // ---- Phase A: issue ALL loads back-to-back (single-visit M stream) ----
    float4 M[NROWS];
    #pragma unroll
    for (int r = 0; r < NROWS; ++r) {
        const int row = clampRow(h0 - 1 + r);
        M[r] = *(const float4*)(base + (size_t)row * ROW_F);
    }

    // Wave-edge neighbor columns: exec-masked loads, 2 lanes per wave.
    // Packed per-lane: left lanes keep E.{y,z,w}, right lanes keep E.{x,y,z}.
    float eA[NROWS], eB[NROWS], eC[NROWS];
    if (lef || rif) {
        const int off = (il || ir) ? 0 : (rif ? 4 : -4);   // clamp at image edge
        float4 Ev[NROWS];
        #pragma unroll
        for (int r = 0; r < NROWS; ++r) {
            const int row = clampRow(h0 - 1 + r);
            Ev[r] = *(const float4*)(base + (size_t)row * ROW_F + off);
        }
        #pragma unroll
        for (int r = 0; r < NROWS; ++r) {
            eA[r] = lef ? Ev[r].y : Ev[r].x;
            eB[r] = lef ? Ev[r].z : Ev[r].y;
            eC[r] = lef ? Ev[r].w : Ev[r].z;
            asm volatile("" :: "v"(eA[r]), "v"(eB[r]), "v"(eC[r]));
        }
    }
    // Liveness barrier: the asm READS every loaded value, so the compiler
    // cannot sink the loads below this point (rule: ablation keep-alive).
    #pragma unroll
    for (int r = 0; r < NROWS; ++r)
        asm volatile("" :: "v"(M[r].x), "v"(M[r].y), "v"(M[r].z), "v"(M[r].w));

    // ---- Phase B: shuffles + median network, rolling vertical window ----
    float mn[3][4], md[3][4], mx[3][4];

    auto triple = [&](int r, int s) {
        const float4 Mv = M[r];
        float l0 = __shfl_up(Mv.y, 1, 64);   // col t*4-3 = left thread's .y
        float l1 = __shfl_up(Mv.z, 1, 64);
        float l2 = __shfl_up(Mv.w, 1, 64);
        float r1 = __shfl_down(Mv.x, 1, 64); // col t*4+4 = right thread's .x
        float r2 = __shfl_down(Mv.y, 1, 64);
        float r3 = __shfl_down(Mv.z, 1, 64);
        if (lef) { l0 = eA[r]; l1 = eB[r]; l2 = eC[r]; }
        if (rif) { r1 = eA[r]; r2 = eB[r]; r3 = eC[r]; }
        if (il)  { l0 = Mv.x; l1 = Mv.y; l2 = Mv.z; }   // replicate left
        if (ir)  { r1 = Mv.y; r2 = Mv.z; r3 = Mv.w; }   // replicate right
        const float l3 = Mv.x;               // in-register neighbors
        const float r0 = Mv.w;
        mn[s][0] = min3f(l0, Mv.x, r0); md[s][0] = med3f(l0, Mv.x, r0); mx[s][0] = max3f(l0, Mv.x, r0);
        mn[s][1] = min3f(l1, Mv.y, r1); md[s][1] = med3f(l1, Mv.y, r1); mx[s][1] = max3f(l1, Mv.y, r1);
        mn[s][2] = min3f(l2, Mv.z, r2); md[s][2] = med3f(l2, Mv.z, r2); mx[s][2] = max3f(l2, Mv.z, r2);
        mn[s][3] = min3f(l3, Mv.w, r3); md[s][3] = med3f(l3, Mv.w, r3); mx[s][3] = max3f(l3, Mv.w, r3);
    };

    triple(0, 0);
    triple(1, 1);

    #pragma unroll
    for (int i = 0; i < TILE_H; ++i) {
        const int h  = h0 + i;
        const int s0 = i % 3, s1 = (i + 1) % 3, s2 = (i + 2) % 3;
        triple(i + 2, s2);

        float4 o;
        o.x = med3f(max3f(mn[s0][0], mn[s1][0], mn[s2][0]),
                    med3f(md[s0][0], md[s1][0], md[s2][0]),
                    min3f(mx[s0][0], mx[s1][0], mx[s2][0]));
        o.y = med3f(max3f(mn[s0][1], mn[s1][1], mn[s2][1]),
                    med3f(md[s0][1], md[s1][1], md[s2][1]),
                    min3f(mx[s0][1], mx[s1][1], mx[s2][1]));
        o.z = med3f(max3f(mn[s0][2], mn[s1][2], mn[s2][2]),
                    med3f(md[s0][2], md[s1][2], md[s2][2]),
                    min3f(mx[s0][2], mx[s1][2], mx[s2][2]));
        o.w = med3f(max3f(mn[s0][3], mn[s1][3], mn[s2][3]),
                    med3f(md[s0][3], md[s1][3], md[s2][3]),
                    min3f(mx[s0][3], mx[s1][3], mx[s2][3]));
        *(float4*)(obase + (size_t)h * ROW_F) = o;
    }
}

extern "C" void kernel_launch(void* const* d_in, const int* in_sizes, int n_in,
                              void* d_out, int out_size, void* d_ws, size_t ws_size,
                              hipStream_t stream) {
    const float* in = (const float*)d_in[0];
    float* out = (float*)d_out;

    const int B = in_sizes[0] / (IMG_H * ROW_F);   // 32

    dim3 grid(1, IMG_H / TILE_H, B);               // (1, 64, 32) = 2048 blocks
    dim3 block(TPB, 1, 1);
    median3x3_v4<<<grid, block, 0, stream>>>(in, out);
}